// Round 3
// baseline (257.298 us; speedup 1.0000x reference)
//
#include <hip/hip_runtime.h>
#include <math.h>

#define EN 16

// mono(x) = exp(-(x*w1 + b1)) . w2 + b2  — fast native exp.
// Gate-safety: angle gates depend only on force *direction*, never on mono
// magnitudes, so __expf's ~1ulp deviation cannot flip a gate.
__device__ __forceinline__ float mono_fast(float x,
    const float* __restrict__ w1, const float* __restrict__ b1,
    const float* __restrict__ w2, const float* __restrict__ b2) {
    float acc = 0.0f;
#pragma unroll
    for (int e = 0; e < EN; ++e) {
        float pre = fmaf(x, w1[e], b1[e]);
        acc = fmaf(__expf(-pre), w2[e], acc);
    }
    return acc + b2[0];
}

// One lane per (agent n, neighbor k): 8 lanes per agent within a wave.
// Round-3 change vs the verified round-0 kernel: __launch_bounds__(256, 8)
// caps VGPR at 64 -> 8 resident waves/SIMD (was 4 at ~100+ VGPR), doubling
// latency hiding; body re-ordered to shrink live ranges (match + fin-mask
// computed right after their inputs load, so ego cols 8..15 and the rec
// entry die early). All arithmetic, gates, and reduction association are
// bit-identical to round-0 (absmax must stay 0.015625).
extern "C" __global__ void __launch_bounds__(256, 8)
sfm_kernel(const float* __restrict__ ego, const float* __restrict__ nei,
           const float* __restrict__ border, const float* __restrict__ rec,
           const float* __restrict__ p_dest, const float* __restrict__ angle,
           const float* __restrict__ rep_w1, const float* __restrict__ rep_b1,
           const float* __restrict__ rep_w2, const float* __restrict__ rep_b2,
           const float* __restrict__ att_w1, const float* __restrict__ att_b1,
           const float* __restrict__ att_w2, const float* __restrict__ att_b2,
           const float* __restrict__ bor_w1, const float* __restrict__ bor_b1,
           const float* __restrict__ bor_w2, const float* __restrict__ bor_b2,
           const float* __restrict__ del_w1, const float* __restrict__ del_b1,
           const float* __restrict__ del_w2, const float* __restrict__ del_b2,
           float* __restrict__ out, int N)
{
    const int gid = blockIdx.x * blockDim.x + threadIdx.x;
    const int n = gid >> 3;
    const int k = gid & 7;
    if (n >= N) return;
    const int lane = threadIdx.x & 63;
    const int gbase = lane & ~7;   // first lane of this agent's 8-lane group

    // neighbor row for (n,k): lane-consecutive 64B stride -> coalesced
    const float* nb = nei + (size_t)n * 128 + (size_t)k * 16;
    float4 na = *(const float4*)nb;          // id, x, y, vx
    const float nvyv = nb[4];                // vy
    const float nid = na.x;

    // recording buffer entry (n,k): 8B/lane consecutive
    float2 rc = *(const float2*)(rec + (size_t)n * 16 + (size_t)k * 2);
    const float bid = rc.x, bct = rc.y;

    // ifin[k] = buf_id[k] present among this agent's nei ids (all-pairs via
    // xor shuffles) — done FIRST so bid/shuffle temps die early.
    bool fin = (bid == nid);
#pragma unroll
    for (int t = 1; t < 8; ++t)
        fin = fin || (bid == __shfl_xor(nid, t));

    // count for slot k of the argsort-select:
    //   first popc(fin) slots take (bct[j-th fin]+1) in j order; rest are 1.0
    //   (new entries and the fill value are both 1.0 -> ifnew is dead code)
    unsigned long long bal = __ballot(fin);
    unsigned finM = (unsigned)((bal >> gbase) & 0xFFull);
    int popcFin = __popc(finM);
    int jsel = 0, cbits = 0;
#pragma unroll
    for (int j = 0; j < 8; ++j) {
        int bit = (finM >> j) & 1;
        if (bit && cbits == k) jsel = j;
        cbits += bit;
    }
    float bctj = __shfl(bct, gbase + jsel);
    float cntk = (k < popcFin) ? (bctj + 1.0f) : 1.0f;

    // ego row (broadcast within group: all 8 lanes same address)
    const float* er = ego + (size_t)n * 16;
    float4 ea = *(const float4*)(er);       // cols 0..3
    float4 eb = *(const float4*)(er + 4);   // cols 4..7
    float4 ec = *(const float4*)(er + 8);   // cols 8..11
    float4 ed = *(const float4*)(er + 12);  // cols 12..15
    const float px = ea.y, py = ea.z, vx = ea.w, vy = eb.x;
    const float speed = sqrtf(vx * vx + vy * vy);

    // idx: neighbor id among ego[:,7:15] — computed immediately so ec/ed die
    bool match = (nid == eb.w) || (nid == ec.x) || (nid == ec.y) || (nid == ec.z)
              || (nid == ec.w) || (nid == ed.x) || (nid == ed.y) || (nid == ed.z);
    const bool idxk = match && (nid != 0.0f);

    const float ang = angle[0];
    const float p0 = p_dest[0], p1 = p_dest[1];

    float rx = idxk ? (na.y - px) : 0.0f;
    float ry = idxk ? (na.z - py) : 0.0f;
    float rn = sqrtf(rx * rx + ry * ry);
    float rns = idxk ? rn : 1.0f;
    float dx = rx / rns, dy = ry / rns;

    // attraction = mono_del(count) * mono_att(rn) * dir
    float att = mono_fast(rn,   att_w1, att_b1, att_w2, att_b2);
    float del = mono_fast(cntk, del_w1, del_b1, del_w2, del_b2);
    float sa = del * att;
    float fax = idxk ? sa * dx : 0.0f;
    float fay = idxk ? sa * dy : 0.0f;

    float nbx = 0.0f, nby = 0.0f;
    {
        float num = vx * fax + vy * fay;
        float fn = sqrtf(fax * fax + fay * fay);
        float den = fmaxf(speed * fn, 1e-8f);
        if (fabsf(num / den) > ang) { nbx += fax; nby += fay; }
    }

    // repulsion
    float sxv = na.w * 0.02f, syv = nvyv * 0.02f;
    float ox = rx + sxv, oy = ry + syv;
    float bsum = rn + (ox * ox + oy * oy) - (sxv * sxv + syv * syv);
    float bgate = idxk ? bsum : 1.0f;
    float bb = sqrtf(fmaxf(bgate, 1e-12f)) * 0.5f;
    float rep = mono_fast(bb, rep_w1, rep_b1, rep_w2, rep_b2);
    float frx = idxk ? rep * dx : 0.0f;
    float fry = idxk ? rep * dy : 0.0f;
    {
        float num = vx * frx + vy * fry;
        float fn = sqrtf(frx * frx + fry * fry);
        float den = fmaxf(speed * fn, 1e-8f);
        if (fabsf(num / den) > ang) { nbx += frx; nby += fry; }
    }

    // border force: y-only; lanes k==0 (border[0]) and k==1 (border[3]) contribute
    float bsel = (k == 0) ? border[0] : border[3];
    float rb = py - bsel;
    float rbn = fabsf(rb);
    float mb = mono_fast(rbn, bor_w1, bor_b1, bor_w2, bor_b2);
    float fby = mb * (rb / rbn);
    float bory = 0.0f;
    {
        float num = vy * fby;
        float den = fmaxf(speed * fabsf(fby), 1e-8f);
        if ((fabsf(num / den) > ang) && (k < 2)) bory = fby;
    }

    // xor-butterfly reduce over the 8-lane group (all lanes end with the sum)
#pragma unroll
    for (int m = 1; m < 8; m <<= 1) {
        nbx  += __shfl_xor(nbx,  m);
        nby  += __shfl_xor(nby,  m);
        bory += __shfl_xor(bory, m);
    }

    // destination force (uniform across group, cheap: compute everywhere)
    float fdx = (p1 * speed - vx) / p0;
    float fdy = (0.0f - vy) / p0;
    float fdex = 0.0f, fdey = 0.0f;
    {
        float num = vx * fdx + vy * fdy;
        float fn = sqrtf(fdx * fdx + fdy * fdy);
        float den = fmaxf(speed * fn, 1e-8f);
        if (fabsf(num / den) > ang) { fdex = fdx; fdey = fdy; }
    }

    // output (N,3,2): lanes 0..5 each write one float (coalesced-ish)
    float wv = (k == 0) ? fdex
             : (k == 1) ? fdey
             : (k == 2) ? nbx
             : (k == 3) ? nby
             : (k == 4) ? 0.0f
             : bory;
    if (k < 6) out[(size_t)n * 6 + k] = wv;
}

extern "C" void kernel_launch(void* const* d_in, const int* in_sizes, int n_in,
                              void* d_out, int out_size, void* d_ws, size_t ws_size,
                              hipStream_t stream) {
    const float* ego    = (const float*)d_in[0];
    const float* nei    = (const float*)d_in[1];
    const float* border = (const float*)d_in[2];
    const float* rec    = (const float*)d_in[3];
    const float* p_dest = (const float*)d_in[4];
    const float* angle  = (const float*)d_in[5];
    const float* rep_w1 = (const float*)d_in[6];
    const float* rep_b1 = (const float*)d_in[7];
    const float* rep_w2 = (const float*)d_in[8];
    const float* rep_b2 = (const float*)d_in[9];
    const float* att_w1 = (const float*)d_in[10];
    const float* att_b1 = (const float*)d_in[11];
    const float* att_w2 = (const float*)d_in[12];
    const float* att_b2 = (const float*)d_in[13];
    const float* bor_w1 = (const float*)d_in[14];
    const float* bor_b1 = (const float*)d_in[15];
    const float* bor_w2 = (const float*)d_in[16];
    const float* bor_b2 = (const float*)d_in[17];
    const float* del_w1 = (const float*)d_in[18];
    const float* del_b1 = (const float*)d_in[19];
    const float* del_w2 = (const float*)d_in[20];
    const float* del_b2 = (const float*)d_in[21];
    float* out = (float*)d_out;

    int N = in_sizes[0] / 16;
    long long threads = (long long)N * 8;
    dim3 grid((unsigned)((threads + 255) / 256));
    sfm_kernel<<<grid, 256, 0, stream>>>(
        ego, nei, border, rec, p_dest, angle,
        rep_w1, rep_b1, rep_w2, rep_b2,
        att_w1, att_b1, att_w2, att_b2,
        bor_w1, bor_b1, bor_w2, bor_b2,
        del_w1, del_b1, del_w2, del_b2,
        out, N);
}

// Round 4
// 254.687 us; speedup vs baseline: 1.0103x; 1.0103x over previous
//
#include <hip/hip_runtime.h>
#include <math.h>

#define EN 16

// mono(x) = exp(-(x*w1 + b1)) . w2 + b2  — fast native exp.
// Gate-safety: angle gates depend only on force *direction*, never on mono
// magnitudes, so __expf's ~1ulp deviation cannot flip a gate.
__device__ __forceinline__ float mono_fast(float x,
    const float* __restrict__ w1, const float* __restrict__ b1,
    const float* __restrict__ w2, const float* __restrict__ b2) {
    float acc = 0.0f;
#pragma unroll
    for (int e = 0; e < EN; ++e) {
        float pre = fmaf(x, w1[e], b1[e]);
        acc = fmaf(__expf(-pre), w2[e], acc);
    }
    return acc + b2[0];
}

// Pre-kernel: del-net mono at x=1.0, with the IDENTICAL instruction sequence
// as the main kernel's mono_fast -> bit-identical value. Used by the main
// kernel's uniform fast path (all cnt values == 1.0).
extern "C" __global__ void sfm_pre(const float* __restrict__ del_w1,
                                   const float* __restrict__ del_b1,
                                   const float* __restrict__ del_w2,
                                   const float* __restrict__ del_b2,
                                   float* __restrict__ ws) {
    if (threadIdx.x == 0 && blockIdx.x == 0)
        ws[0] = mono_fast(1.0f, del_w1, del_b1, del_w2, del_b2);
}

// One lane per (agent n, neighbor k): 8 lanes per agent within a wave.
// Round-4 change vs verified round-0: wave-uniform fast path for the
// recording-buffer logic. Two ballots detect (all bid==0) && (no nid==0);
// in that case fin is provably false for every lane -> finM==0 ->
// cntk==1.0 and del=mono(1.0) (precomputed, bit-identical). Skips the
// 7-shuffle fin chain, ballot/jsel select, dynamic shuffle, and one full
// 16-exp mono per lane. Slow path is the unmodified round-0 code, so the
// kernel remains correct for arbitrary recording_time/nei contents.
extern "C" __global__ void __launch_bounds__(256)
sfm_kernel(const float* __restrict__ ego, const float* __restrict__ nei,
           const float* __restrict__ border, const float* __restrict__ rec,
           const float* __restrict__ p_dest, const float* __restrict__ angle,
           const float* __restrict__ rep_w1, const float* __restrict__ rep_b1,
           const float* __restrict__ rep_w2, const float* __restrict__ rep_b2,
           const float* __restrict__ att_w1, const float* __restrict__ att_b1,
           const float* __restrict__ att_w2, const float* __restrict__ att_b2,
           const float* __restrict__ bor_w1, const float* __restrict__ bor_b1,
           const float* __restrict__ bor_w2, const float* __restrict__ bor_b2,
           const float* __restrict__ del_w1, const float* __restrict__ del_b1,
           const float* __restrict__ del_w2, const float* __restrict__ del_b2,
           const float* __restrict__ del1p,
           float* __restrict__ out, int N)
{
    const int gid = blockIdx.x * blockDim.x + threadIdx.x;
    const int n = gid >> 3;
    const int k = gid & 7;
    if (n >= N) return;
    const int lane = threadIdx.x & 63;
    const int gbase = lane & ~7;   // first lane of this agent's 8-lane group

    // neighbor row for (n,k): lane-consecutive 64B stride -> coalesced
    const float* nb = nei + (size_t)n * 128 + (size_t)k * 16;
    float4 na = *(const float4*)nb;          // id, x, y, vx
    const float nvyv = nb[4];                // vy
    const float nid = na.x;

    // recording buffer entry (n,k): 8B/lane consecutive
    float2 rc = *(const float2*)(rec + (size_t)n * 16 + (size_t)k * 2);
    const float bid = rc.x, bct = rc.y;

    // ---- uniform fast path test (wave-wide, no divergence) ----
    // fin[k] = (bid[k] matches some nid of the group). If every bid==0 and
    // no nid==0, fin is false everywhere -> finM==0 for all groups.
    unsigned long long zb = __ballot(bid != 0.0f);
    unsigned long long zn = __ballot(nid == 0.0f);

    float cntk, delv;
    if (__builtin_expect((zb | zn) == 0ull, 1)) {
        // popcFin==0 -> every slot takes the fill value 1.0
        cntk = 1.0f;
        delv = del1p ? del1p[0]
                     : mono_fast(1.0f, del_w1, del_b1, del_w2, del_b2);
    } else {
        // ---- full (verified round-0) path ----
        bool fin = (bid == nid);
#pragma unroll
        for (int t = 1; t < 8; ++t)
            fin = fin || (bid == __shfl_xor(nid, t));

        unsigned long long bal = __ballot(fin);
        unsigned finM = (unsigned)((bal >> gbase) & 0xFFull);
        int popcFin = __popc(finM);
        int jsel = 0, cbits = 0;
#pragma unroll
        for (int j = 0; j < 8; ++j) {
            int bit = (finM >> j) & 1;
            if (bit && cbits == k) jsel = j;
            cbits += bit;
        }
        float bctj = __shfl(bct, gbase + jsel);
        cntk = (k < popcFin) ? (bctj + 1.0f) : 1.0f;
        delv = mono_fast(cntk, del_w1, del_b1, del_w2, del_b2);
    }

    // ego row (broadcast within group: all 8 lanes same address)
    const float* er = ego + (size_t)n * 16;
    float4 ea = *(const float4*)(er);       // cols 0..3
    float4 eb = *(const float4*)(er + 4);   // cols 4..7
    float4 ec = *(const float4*)(er + 8);   // cols 8..11
    float4 ed = *(const float4*)(er + 12);  // cols 12..15
    const float px = ea.y, py = ea.z, vx = ea.w, vy = eb.x;
    const float speed = sqrtf(vx * vx + vy * vy);

    // idx: neighbor id among ego[:,7:15]
    bool match = (nid == eb.w) || (nid == ec.x) || (nid == ec.y) || (nid == ec.z)
              || (nid == ec.w) || (nid == ed.x) || (nid == ed.y) || (nid == ed.z);
    const bool idxk = match && (nid != 0.0f);

    const float ang = angle[0];
    const float p0 = p_dest[0], p1 = p_dest[1];

    float rx = idxk ? (na.y - px) : 0.0f;
    float ry = idxk ? (na.z - py) : 0.0f;
    float rn = sqrtf(rx * rx + ry * ry);
    float rns = idxk ? rn : 1.0f;
    float dx = rx / rns, dy = ry / rns;

    // attraction = mono_del(count) * mono_att(rn) * dir
    float att = mono_fast(rn, att_w1, att_b1, att_w2, att_b2);
    float sa = delv * att;
    float fax = idxk ? sa * dx : 0.0f;
    float fay = idxk ? sa * dy : 0.0f;

    float nbx = 0.0f, nby = 0.0f;
    {
        float num = vx * fax + vy * fay;
        float fn = sqrtf(fax * fax + fay * fay);
        float den = fmaxf(speed * fn, 1e-8f);
        if (fabsf(num / den) > ang) { nbx += fax; nby += fay; }
    }

    // repulsion
    float sxv = na.w * 0.02f, syv = nvyv * 0.02f;
    float ox = rx + sxv, oy = ry + syv;
    float bsum = rn + (ox * ox + oy * oy) - (sxv * sxv + syv * syv);
    float bgate = idxk ? bsum : 1.0f;
    float bb = sqrtf(fmaxf(bgate, 1e-12f)) * 0.5f;
    float rep = mono_fast(bb, rep_w1, rep_b1, rep_w2, rep_b2);
    float frx = idxk ? rep * dx : 0.0f;
    float fry = idxk ? rep * dy : 0.0f;
    {
        float num = vx * frx + vy * fry;
        float fn = sqrtf(frx * frx + fry * fry);
        float den = fmaxf(speed * fn, 1e-8f);
        if (fabsf(num / den) > ang) { nbx += frx; nby += fry; }
    }

    // border force: y-only; lanes k==0 (border[0]) and k==1 (border[3]) contribute
    float bsel = (k == 0) ? border[0] : border[3];
    float rb = py - bsel;
    float rbn = fabsf(rb);
    float mb = mono_fast(rbn, bor_w1, bor_b1, bor_w2, bor_b2);
    float fby = mb * (rb / rbn);
    float bory = 0.0f;
    {
        float num = vy * fby;
        float den = fmaxf(speed * fabsf(fby), 1e-8f);
        if ((fabsf(num / den) > ang) && (k < 2)) bory = fby;
    }

    // xor-butterfly reduce over the 8-lane group (all lanes end with the sum)
#pragma unroll
    for (int m = 1; m < 8; m <<= 1) {
        nbx  += __shfl_xor(nbx,  m);
        nby  += __shfl_xor(nby,  m);
        bory += __shfl_xor(bory, m);
    }

    // destination force (uniform across group, cheap: compute everywhere)
    float fdx = (p1 * speed - vx) / p0;
    float fdy = (0.0f - vy) / p0;
    float fdex = 0.0f, fdey = 0.0f;
    {
        float num = vx * fdx + vy * fdy;
        float fn = sqrtf(fdx * fdx + fdy * fdy);
        float den = fmaxf(speed * fn, 1e-8f);
        if (fabsf(num / den) > ang) { fdex = fdx; fdey = fdy; }
    }

    // output (N,3,2): lanes 0..5 each write one float (coalesced-ish)
    float wv = (k == 0) ? fdex
             : (k == 1) ? fdey
             : (k == 2) ? nbx
             : (k == 3) ? nby
             : (k == 4) ? 0.0f
             : bory;
    if (k < 6) out[(size_t)n * 6 + k] = wv;
}

extern "C" void kernel_launch(void* const* d_in, const int* in_sizes, int n_in,
                              void* d_out, int out_size, void* d_ws, size_t ws_size,
                              hipStream_t stream) {
    const float* ego    = (const float*)d_in[0];
    const float* nei    = (const float*)d_in[1];
    const float* border = (const float*)d_in[2];
    const float* rec    = (const float*)d_in[3];
    const float* p_dest = (const float*)d_in[4];
    const float* angle  = (const float*)d_in[5];
    const float* rep_w1 = (const float*)d_in[6];
    const float* rep_b1 = (const float*)d_in[7];
    const float* rep_w2 = (const float*)d_in[8];
    const float* rep_b2 = (const float*)d_in[9];
    const float* att_w1 = (const float*)d_in[10];
    const float* att_b1 = (const float*)d_in[11];
    const float* att_w2 = (const float*)d_in[12];
    const float* att_b2 = (const float*)d_in[13];
    const float* bor_w1 = (const float*)d_in[14];
    const float* bor_b1 = (const float*)d_in[15];
    const float* bor_w2 = (const float*)d_in[16];
    const float* bor_b2 = (const float*)d_in[17];
    const float* del_w1 = (const float*)d_in[18];
    const float* del_b1 = (const float*)d_in[19];
    const float* del_w2 = (const float*)d_in[20];
    const float* del_b2 = (const float*)d_in[21];
    float* out = (float*)d_out;

    int N = in_sizes[0] / 16;

    // precompute del-mono(1.0) into workspace (bit-identical sequence);
    // same stream -> ordered before the main kernel, graph-capture safe.
    float* del1p = nullptr;
    if (ws_size >= sizeof(float)) {
        del1p = (float*)d_ws;
        sfm_pre<<<1, 64, 0, stream>>>(del_w1, del_b1, del_w2, del_b2, del1p);
    }

    long long threads = (long long)N * 8;
    dim3 grid((unsigned)((threads + 255) / 256));
    sfm_kernel<<<grid, 256, 0, stream>>>(
        ego, nei, border, rec, p_dest, angle,
        rep_w1, rep_b1, rep_w2, rep_b2,
        att_w1, att_b1, att_w2, att_b2,
        bor_w1, bor_b1, bor_w2, bor_b2,
        del_w1, del_b1, del_w2, del_b2,
        del1p, out, N);
}